// Round 1
// baseline (191.187 us; speedup 1.0000x reference)
//
#include <hip/hip_runtime.h>

// MLPLowRankPredictor: FastFood (B,H,P,G,H,S) low-rank weight perturbation + 3-layer MLP.
// SEQ=64 BATCH=32 -> N=2048 tokens. Z=128, X=32, H=128, Y=16.
// Blocks: wd0: 0..31 (4 rows x 32 cols each), bd0: 32, wd1: 33..160 (1 row each),
//         bd1: 161, wd2: 162..177 (1 row each), bd2: 178 (first 16 elems).
// Strategy: lane=token, FWHT128 fully in registers; permutation via one LDS
// round trip per (wave, block); 3 kernels (layer dependency), h1/h2 in d_ws.

#define ZD 128
#define XD 32
#define HD 128
#define YD 16

__device__ __forceinline__ void fwht128(float v[128]) {
#pragma unroll
  for (int s = 1; s < 128; s <<= 1) {
#pragma unroll
    for (int p = 0; p < 128; p++) {
      if ((p & s) == 0) {
        float a = v[p], b = v[p + s];
        v[p] = a + b;
        v[p + s] = a - b;
      }
    }
  }
}

__device__ __forceinline__ void load128(float v[128], const float* __restrict__ src) {
  const float4* s4 = (const float4*)src;
#pragma unroll
  for (int k = 0; k < 32; k++) {
    float4 f = s4[k];
    v[4 * k + 0] = f.x; v[4 * k + 1] = f.y; v[4 * k + 2] = f.z; v[4 * k + 3] = f.w;
  }
}

// v holds z on entry; on exit v = ffS * FWHT( ffG * perm( FWHT( ffB * z ) ) )
// (the final /128 is applied by the consumer).
__device__ __forceinline__ void ff_block(float v[128], float* lds, int lane,
    const float* __restrict__ ffB, const float* __restrict__ ffG,
    const float* __restrict__ ffS, const int* __restrict__ ffP, int j) {
  const float* Bj = ffB + j * ZD;
  const float* Gj = ffG + j * ZD;
  const float* Sj = ffS + j * ZD;
  const int*   Pj = ffP + j * ZD;
#pragma unroll
  for (int k = 0; k < 128; k++) v[k] *= Bj[k];   // uniform -> s_load
  fwht128(v);
  __syncthreads();                                // WAR vs any previous lds reads
#pragma unroll
  for (int k = 0; k < 128; k++) lds[k * 64 + lane] = v[k];  // conflict-free
  __syncthreads();
#pragma unroll
  for (int k = 0; k < 128; k++) v[k] = Gj[k] * lds[Pj[k] * 64 + lane];
  fwht128(v);
#pragma unroll
  for (int k = 0; k < 128; k++) v[k] *= Sj[k];
}

__global__ __launch_bounds__(64) void k1_layer0(
    const float* __restrict__ x, const float* __restrict__ z,
    const float* __restrict__ W0, const float* __restrict__ b0,
    const float* __restrict__ ffB, const float* __restrict__ ffG,
    const float* __restrict__ ffS, const int* __restrict__ ffP,
    float* __restrict__ h1) {
  __shared__ float lds[128 * 64];
  const int lane = threadIdx.x;
  const int tg = blockIdx.x;   // token group 0..31
  const int b  = blockIdx.y;   // weight block 0..31 -> output rows 4b..4b+3
  const int t = tg * 64 + lane;

  float xi[32];
  {
    const float4* x4 = (const float4*)(x + (size_t)t * XD);
#pragma unroll
    for (int k = 0; k < 8; k++) {
      float4 f = x4[k];
      xi[4 * k] = f.x; xi[4 * k + 1] = f.y; xi[4 * k + 2] = f.z; xi[4 * k + 3] = f.w;
    }
  }

  float v[128];
  load128(v, z + (size_t)t * ZD);
  ff_block(v, lds, lane, ffB, ffG, ffS, ffP, b);

  float wdot[4], base[4];
#pragma unroll
  for (int r = 0; r < 4; r++) {
    float aw = 0.f, ab = 0.f;
#pragma unroll
    for (int i = 0; i < 32; i++) {
      aw += v[r * 32 + i] * xi[i];
      ab += W0[(4 * b + r) * 32 + i] * xi[i];   // uniform -> s_load
    }
    wdot[r] = aw; base[r] = ab;
  }

  // bias block 32 (recomputed per wave; K1 is occupancy-starved so it's free)
  load128(v, z + (size_t)t * ZD);
  ff_block(v, lds, lane, ffB, ffG, ffS, ffP, 32);

  // extract v[4b+r] (runtime-uniform index) via LDS
  __syncthreads();
#pragma unroll
  for (int k = 0; k < 128; k++) lds[k * 64 + lane] = v[k];
  __syncthreads();
  float4 o;
  float* op = &o.x;
#pragma unroll
  for (int r = 0; r < 4; r++) {
    float bd = lds[(4 * b + r) * 64 + lane];
    float val = base[r] + b0[4 * b + r] + (wdot[r] + bd) * (1.0f / 128.0f);
    op[r] = fmaxf(val, 0.f);   // relu applied here; K2 reads h1 directly
  }
  *(float4*)(h1 + (size_t)t * HD + 4 * b) = o;
}

__global__ __launch_bounds__(64) void k2_layer1(
    const float* __restrict__ z,
    const float* __restrict__ W1, const float* __restrict__ b1,
    const float* __restrict__ ffB, const float* __restrict__ ffG,
    const float* __restrict__ ffS, const int* __restrict__ ffP,
    const float* __restrict__ h1,
    float* __restrict__ h2_part, float* __restrict__ h2_bias) {
  __shared__ float lds[128 * 64];
  const int lane = threadIdx.x;
  const int tg = blockIdx.x;   // 0..31
  const int jr = blockIdx.y;   // 0..127 weight row, 128 = bias block
  const int t = tg * 64 + lane;

  float v[128];
  load128(v, z + (size_t)t * ZD);
  if (jr < 128) {
    ff_block(v, lds, lane, ffB, ffG, ffS, ffP, 33 + jr);
    // dot with h1 (transient float4 loads, never register-resident) + base W1 row
    const float4* h4 = (const float4*)(h1 + (size_t)t * HD);
    const float* W1r = W1 + (size_t)jr * 128;
    float aw0 = 0.f, aw1 = 0.f, ab0 = 0.f, ab1 = 0.f;
#pragma unroll
    for (int k = 0; k < 32; k++) {
      float4 h = h4[k];
      aw0 += v[4 * k + 0] * h.x + v[4 * k + 2] * h.z;
      aw1 += v[4 * k + 1] * h.y + v[4 * k + 3] * h.w;
      ab0 += W1r[4 * k + 0] * h.x + W1r[4 * k + 2] * h.z;
      ab1 += W1r[4 * k + 1] * h.y + W1r[4 * k + 3] * h.w;
    }
    float val = (ab0 + ab1) + b1[jr] + (aw0 + aw1) * (1.0f / 128.0f);
    h2_part[(size_t)t * HD + jr] = val;   // pre-relu partial (bias added in K3)
  } else {
    ff_block(v, lds, lane, ffB, ffG, ffS, ffP, 161);
    float4* o4 = (float4*)(h2_bias + (size_t)t * HD);
#pragma unroll
    for (int k = 0; k < 32; k++) {
      float4 o = make_float4(v[4 * k] * (1.0f / 128.0f), v[4 * k + 1] * (1.0f / 128.0f),
                             v[4 * k + 2] * (1.0f / 128.0f), v[4 * k + 3] * (1.0f / 128.0f));
      o4[k] = o;
    }
  }
}

__global__ __launch_bounds__(64) void k3_layer2(
    const float* __restrict__ z,
    const float* __restrict__ W2, const float* __restrict__ b2,
    const float* __restrict__ ffB, const float* __restrict__ ffG,
    const float* __restrict__ ffS, const int* __restrict__ ffP,
    const float* __restrict__ h2_part, const float* __restrict__ h2_bias,
    float* __restrict__ out) {
  __shared__ float lds[128 * 64];
  const int lane = threadIdx.x;
  const int tg = blockIdx.x;   // 0..31
  const int b  = blockIdx.y;   // 0..15 output row
  const int t = tg * 64 + lane;

  float v[128];
  load128(v, z + (size_t)t * ZD);
  ff_block(v, lds, lane, ffB, ffG, ffS, ffP, 162 + b);

  const float4* p4 = (const float4*)(h2_part + (size_t)t * HD);
  const float4* q4 = (const float4*)(h2_bias + (size_t)t * HD);
  const float* W2r = W2 + (size_t)b * 128;
  float aw = 0.f, ab = 0.f;
#pragma unroll
  for (int k = 0; k < 32; k++) {
    float4 p = p4[k], q = q4[k];
    float e0 = fmaxf(p.x + q.x, 0.f), e1 = fmaxf(p.y + q.y, 0.f);
    float e2 = fmaxf(p.z + q.z, 0.f), e3 = fmaxf(p.w + q.w, 0.f);
    aw += v[4 * k] * e0 + v[4 * k + 1] * e1 + v[4 * k + 2] * e2 + v[4 * k + 3] * e3;
    ab += W2r[4 * k] * e0 + W2r[4 * k + 1] * e1 + W2r[4 * k + 2] * e2 + W2r[4 * k + 3] * e3;
  }

  // bias block 178 (recomputed; K3 fills only half the SIMDs anyway)
  load128(v, z + (size_t)t * ZD);
  ff_block(v, lds, lane, ffB, ffG, ffS, ffP, 178);
  __syncthreads();
#pragma unroll
  for (int k = 0; k < 16; k++) lds[k * 64 + lane] = v[k];   // only first 16 used
  __syncthreads();
  float bd2 = lds[b * 64 + lane];

  out[(size_t)t * YD + b] = ab + b2[b] + (aw + bd2) * (1.0f / 128.0f);
}

extern "C" void kernel_launch(void* const* d_in, const int* in_sizes, int n_in,
                              void* d_out, int out_size, void* d_ws, size_t ws_size,
                              hipStream_t stream) {
  const float* x  = (const float*)d_in[0];
  const float* z  = (const float*)d_in[1];
  const float* W0 = (const float*)d_in[2];
  const float* b0 = (const float*)d_in[3];
  const float* W1 = (const float*)d_in[4];
  const float* b1 = (const float*)d_in[5];
  const float* W2 = (const float*)d_in[6];
  const float* b2 = (const float*)d_in[7];
  const float* fB = (const float*)d_in[8];
  const float* fG = (const float*)d_in[9];
  const float* fS = (const float*)d_in[10];
  const int*   fP = (const int*)d_in[11];
  float* out = (float*)d_out;

  float* h1      = (float*)d_ws;          // 2048*128 f32 = 1 MB (post-relu)
  float* h2_part = h1 + 2048 * 128;       // 1 MB (pre-relu, W1*h + b1 + wd part)
  float* h2_bias = h2_part + 2048 * 128;  // 1 MB (bd1 part)

  k1_layer0<<<dim3(32, 32), 64, 0, stream>>>(x, z, W0, b0, fB, fG, fS, fP, h1);
  k2_layer1<<<dim3(32, 129), 64, 0, stream>>>(z, W1, b1, fB, fG, fS, fP, h1, h2_part, h2_bias);
  k3_layer2<<<dim3(32, 16), 64, 0, stream>>>(z, W2, b2, fB, fG, fS, fP, h2_part, h2_bias, out);
}